// Round 5
// baseline (363.316 us; speedup 1.0000x reference)
//
#include <hip/hip_runtime.h>
#include <math.h>

// Problem constants (fixed by reference): B=1024, NMAX=128, D=256, NUM=4
#define BB   1024
#define DD   256
#define LOGD 5.5451774444795624753f   // log(256)
#define RST  260                      // red row stride (floats): 260=4 mod 32 -> uniform banks

typedef __attribute__((ext_vector_type(8))) short short8;   // 8 bf16 = 4 VGPRs
typedef __attribute__((ext_vector_type(4))) float f32x4;    // MFMA acc

__device__ __forceinline__ float wave_sum(float v){
  #pragma unroll
  for (int off=32; off>0; off>>=1) v += __shfl_xor(v, off, 64);
  return v;
}
__device__ __forceinline__ float wave_max(float v){
  #pragma unroll
  for (int off=32; off>0; off>>=1) v = fmaxf(v, __shfl_xor(v, off, 64));
  return v;
}
// 16-lane-group sum: reduces 4 rows of a wave simultaneously (4-step chain)
__device__ __forceinline__ float grp_sum(float v){
  v += __shfl_xor(v, 1, 64);
  v += __shfl_xor(v, 2, 64);
  v += __shfl_xor(v, 4, 64);
  v += __shfl_xor(v, 8, 64);
  return v;
}
__device__ __forceinline__ float fast_tanh(float x){
  return 1.0f - 2.0f/(__expf(2.0f*x)+1.0f);
}
__device__ __forceinline__ unsigned short f2bf(float f){
  unsigned int u = __float_as_uint(f);
  unsigned int r = u + 0x7FFFu + ((u >> 16) & 1u);   // RNE
  return (unsigned short)(r >> 16);
}
// s16 codecs. A/log-state at scale 512 (abs err ~1e-3, range (-64,+16)).
// z at scale 4096 (|z| <= sum r_k ~ 3, abs err 1.2e-4).
__device__ __forceinline__ float decq(int q16){ return (float)q16 * (1.0f/512.0f); }
__device__ __forceinline__ int   zenc(float z){
  float t = fmaf(z, 4096.0f, 12582912.0f);   // RNE via 1.5*2^23 magic add
  return __float_as_int(t) - 0x4B400000;
}
__device__ __forceinline__ float zdec(int q){ return (float)q * (1.0f/4096.0f); }
__device__ __forceinline__ int lo16(unsigned u){ return ((int)(u<<16))>>16; }
__device__ __forceinline__ int hi16(unsigned u){ return ((int)u)>>16; }
__device__ __forceinline__ unsigned pk2(int a, int b){
  return ((unsigned)a & 0xffffu) | ((unsigned)b << 16);
}
// packed saturating s16 add: lt = sat(y_s16 + off_s16); sat(-32768)=-64.0 (==0 mass)
__device__ __forceinline__ unsigned pkadd_sat(unsigned a, unsigned b){
  unsigned d; asm("v_pk_add_i16 %0, %1, %2 clamp" : "=v"(d) : "v"(a), "v"(b)); return d;
}

// ---- K_pre: fused prologue (castW + bounds + params + logits zero) ----
// blocks 0..63: W1 cast; 64..68: segment bounds; 69: params; 70..: zero logits.
__global__ void k_pre(const float* __restrict__ W1, unsigned short* __restrict__ w1b,
                      const int* __restrict__ batch, int T, int* __restrict__ starts,
                      const float* __restrict__ rho, const float* __restrict__ a1,
                      const float* __restrict__ a2, const float* __restrict__ a3,
                      float* __restrict__ P, float* __restrict__ logits)
{
  const int blk = blockIdx.x, tid = threadIdx.x;
  if (blk < 64){
    const int t = blk*256 + tid;
    #pragma unroll
    for (int i=0;i<2;i++){
      const int idx = (t*2 + i)*4;
      const float4 v = *(const float4*)(W1 + idx);
      *(ushort4*)(w1b + idx) = make_ushort4(f2bf(v.x), f2bf(v.y), f2bf(v.z), f2bf(v.w));
    }
  } else if (blk < 69){
    const int b = (blk-64)*256 + tid;
    if (b <= BB){
      int lo = 0, hi = T;
      while (lo < hi){ int mid = (lo+hi)>>1; if (batch[mid] < b) lo = mid+1; else hi = mid; }
      starts[b] = lo;
    }
  } else if (blk == 69){
    if (tid == 0){
      float lm = -LOGD, z1 = 0.f;
      for (int k=0;k<4;k++){
        float r  = log1pf(expf(rho[k]));
        float b1 = log1pf(expf(a1[k]));
        float b2 = log1pf(expf(a2[k]));
        float b3 = log1pf(expf(a3[k]));
        P[k]    = r;
        P[4+k]  = 1.f/(b1+r);
        P[8+k]  = 1.f/(b2+r);
        P[12+k] = lm;              // mu used by S-update of iteration k
        P[16+k] = b3;
        P[20+k] = 1.f/(b3+r);
        float lmn = (b3*(-LOGD) - z1 + r*lm)/(b3+r);
        z1 += r*(expf(lmn)-expf(lm));
        lm = lmn;
      }
    }
  } else {
    // zero logits (replaces separate hipMemsetAsync launch)
    const int i = (blk-70)*1024 + tid*4;
    if (i + 3 < T){
      *(float4*)(logits + i) = make_float4(0.f,0.f,0.f,0.f);
    } else {
      for (int j=0; j<4 && i+j < T; j++) logits[i+j] = 0.f;
    }
  }
}

// ---- K2: fused MLP via bf16 MFMA (unchanged structure) ----
#define LPW 72
__global__ __launch_bounds__(512, 2) void k_mlp(
    const float* __restrict__ x, const unsigned short* __restrict__ w1b,
    const float* __restrict__ W2, float* __restrict__ logits, int T)
{
  __shared__ unsigned short Xs[128*LPW];
  __shared__ unsigned short Ws[128*LPW];
  __shared__ float lred[128];
  const int by = blockIdx.x;
  const int bx = blockIdx.y;
  const int tid = threadIdx.x;
  if (tid < 128) lred[tid] = 0.f;

  const int l = tid & 63;
  const int w = tid >> 6;
  const int wm = w >> 2;
  const int wn = w & 3;
  const int lr = l & 15, quad = l >> 4;
  const int srow = tid >> 2;
  const int sseg = tid & 3;
  const int wrow = tid >> 3;
  const int wseg = tid & 7;

  f32x4 acc[4][2];
  #pragma unroll
  for (int mi=0;mi<4;mi++)
    #pragma unroll
    for (int ni=0;ni<2;ni++) acc[mi][ni] = (f32x4){0.f,0.f,0.f,0.f};

  for (int kt=0; kt<4; kt++){
    const int k0 = kt*64;
    {
      const int grow = bx*128 + srow;
      #pragma unroll
      for (int i=0;i<4;i++){
        float4 v = make_float4(0.f,0.f,0.f,0.f);
        if (grow < T) v = *(const float4*)(x + (size_t)grow*DD + k0 + sseg*16 + i*4);
        *(ushort4*)&Xs[srow*LPW + sseg*16 + i*4] =
            make_ushort4(f2bf(v.x), f2bf(v.y), f2bf(v.z), f2bf(v.w));
      }
    }
    #pragma unroll
    for (int h=0; h<2; h++){
      const int r = h*64 + wrow;
      *(short8*)&Ws[r*LPW + wseg*8] =
          *(const short8*)(w1b + (size_t)(by*128 + r)*DD + k0 + wseg*8);
    }
    __syncthreads();
    #pragma unroll
    for (int ks=0; ks<2; ks++){
      short8 afr[4], bfr[2];
      #pragma unroll
      for (int mi=0;mi<4;mi++)
        afr[mi] = *(const short8*)&Xs[(wm*64 + mi*16 + lr)*LPW + ks*32 + quad*8];
      #pragma unroll
      for (int ni=0;ni<2;ni++)
        bfr[ni] = *(const short8*)&Ws[(wn*32 + ni*16 + lr)*LPW + ks*32 + quad*8];
      #pragma unroll
      for (int mi=0;mi<4;mi++)
        #pragma unroll
        for (int ni=0;ni<2;ni++)
          acc[mi][ni] = __builtin_amdgcn_mfma_f32_16x16x32_bf16(afr[mi], bfr[ni], acc[mi][ni], 0, 0, 0);
    }
    __syncthreads();
  }

  float w2v[2];
  #pragma unroll
  for (int ni=0;ni<2;ni++) w2v[ni] = W2[by*128 + wn*32 + ni*16 + lr];
  #pragma unroll
  for (int mi=0;mi<4;mi++){
    float p[4];
    #pragma unroll
    for (int v=0; v<4; v++){
      p[v] = fast_tanh(acc[mi][0][v])*w2v[0] + fast_tanh(acc[mi][1][v])*w2v[1];
      #pragma unroll
      for (int off=1; off<16; off<<=1) p[v] += __shfl_xor(p[v], off, 64);
    }
    if (lr == 0){
      #pragma unroll
      for (int v=0; v<4; v++)
        atomicAdd(&lred[wm*64 + mi*16 + quad*4 + v], p[v]);
    }
  }
  __syncthreads();
  if (tid < 128){
    const int grow = bx*128 + tid;
    if (grow < T) atomicAdd(logits + grow, lred[tid]);
  }
}

// ---- K4: BADMM solver (round-4 structure, launch-bounds fix) ----
// Round-4 post-mortem: structure works (126us) but VGPR_Count=64 + 75MB
// scratch writes = allocator spilled ~36 regs/thread. Unifying theory for
// rounds 1-4: this toolchain treats __launch_bounds__ arg2 as MIN BLOCKS
// PER CU (CUDA semantics): (1024,8)->VGPR 32; (512,4)->32 waves/CU->cap 64.
// Fix: (512,2) -> 2 blocks/CU -> 16 waves/CU -> 128-VGPR cap; demand ~110
// (ap 32 + zp 32 + sp 16 + transients) fits -> no spill, same residency.
__global__ __launch_bounds__(512, 2) void k_solver(
    const float* __restrict__ x, const float* __restrict__ logits,
    const int* __restrict__ starts, const float* __restrict__ P,
    float* __restrict__ out)
{
  __shared__ __align__(16) float red[32*RST];   // 33280 B: column partials
  __shared__ __align__(16) float colv[DD];      // 1 KB: column log-sum
  const int b = blockIdx.x;
  const int start = starts[b];
  const int len = starts[b+1] - start;
  const int tid = threadIdx.x;
  const int w = tid >> 6, l = tid & 63;
  const int sub = l >> 4;          // row within 4-row group
  const int c0  = l & 15;          // column slice
  const int n0 = w*16;
  int nv = len - n0; nv = nv < 0 ? 0 : (nv > 16 ? 16 : nv);

  // scalar params (wave-uniform s_loads)
  const float r0=P[0], r1=P[1], r2=P[2], r3=P[3];
  const float i10=P[4], i11=P[5], i12=P[6];
  const float i20=P[8], i21=P[9], i22=P[10], i23=P[11];
  const float mu0=P[12], mu1=P[13], mu2=P[14];
  const float b30=P[16], b31=P[17], b32=P[18];
  const float e30=P[20], e31=P[21], e32=P[22];

  // ---- fused segment softmax (per-wave redundant) ----
  const float* lg = logits + start;
  float v0 = (l      < len) ? lg[l]    : -3.0e38f;
  float v1 = (l+64   < len) ? lg[l+64] : -3.0e38f;
  float sm = wave_max(fmaxf(v0,v1));
  float se0 = (l    < len) ? __expf(v0-sm) : 0.f;
  float se1 = (l+64 < len) ? __expf(v1-sm) : 0.f;
  float ssum0 = wave_sum(se0+se1);
  const float sinv = 1.f/(ssum0 + 1e-16f);
  const float esel = (n0 < 64) ? se0 : se1;   // rows n0..n0+15 on one side of 64

  // per-group (4 rows/wave-group) state, lane-redundant within 16-lane group
  float slqg[4], etag[4], z2g[4];
  uint2 ap[4][4];   // s16 log-state, [group][q]: 32 VGPR
  uint2 zp[4][4];   // s16 dual z:               32 VGPR
  #pragma unroll
  for (int g=0; g<4; g++){
    const int row = n0 + 4*g + sub;
    const float ev = __shfl(esel, row & 63, 64);
    const float lq = __logf(ev*sinv + 1e-8f);
    slqg[g] = lq; etag[g] = lq; z2g[g] = 0.f;
    #pragma unroll
    for (int q=0;q<4;q++){ zp[g][q].x = 0u; zp[g][q].y = 0u; }
  }

  const float* xbase = x + (size_t)(start + n0 + sub)*DD + 4*c0;

  // ================= sweep 0: T(0) + colsum for S(0) =================
  {
    float sp[16];
    #pragma unroll
    for (int j=0;j<16;j++) sp[j]=0.f;
    #pragma unroll
    for (int g=0; g<4; g++){
      if (4*g + sub < nv){
        const float* xp = xbase + (size_t)(4*g)*DD;
        const float a0 = slqg[g] - LOGD;
        float ss = 0.f;
        #pragma unroll
        for (int q=0;q<4;q++){
          const float4 xv = *(const float4*)(xp + 64*q);
          const float xvv[4] = {xv.x, xv.y, xv.z, xv.w};
          int ny[4];
          #pragma unroll
          for (int j=0;j<4;j++){
            const float y = (xvv[j] + r0*a0) * i20;
            ss += __expf(y);
            ny[j] = __float2int_rn(y*512.f);
          }
          ap[g][q].x = pk2(ny[0],ny[1]);
          ap[g][q].y = pk2(ny[2],ny[3]);
        }
        ss = grp_sum(ss);
        const float off = etag[g] - __logf(ss);
        const int offi = __float2int_rn(fmaxf(off, -56.f)*512.f);
        const unsigned offpk = pk2(offi, offi);
        #pragma unroll
        for (int q=0;q<4;q++){
          ap[g][q].x = pkadd_sat(ap[g][q].x, offpk);
          ap[g][q].y = pkadd_sat(ap[g][q].y, offpk);
          sp[4*q+0] += __expf((r0*decq(lo16(ap[g][q].x))) * i10);
          sp[4*q+1] += __expf((r0*decq(hi16(ap[g][q].x))) * i10);
          sp[4*q+2] += __expf((r0*decq(lo16(ap[g][q].y))) * i10);
          sp[4*q+3] += __expf((r0*decq(hi16(ap[g][q].y))) * i10);
        }
        const float en = (b30*slqg[g] - z2g[g] + r0*etag[g]) * e30;
        z2g[g] += r0*(__expf(en) - __expf(etag[g]));
        etag[g] = en;
      }
    }
    #pragma unroll
    for (int q=0;q<4;q++)
      *(float4*)&red[(4*w+sub)*RST + 64*q + 4*c0] =
          make_float4(sp[4*q], sp[4*q+1], sp[4*q+2], sp[4*q+3]);
  }
  __syncthreads();
  if (tid < DD){
    float s = 0.f;
    #pragma unroll
    for (int i=0;i<32;i++) s += red[i*RST + tid];
    colv[tid] = __logf(s);
  }
  __syncthreads();

  // ============ sweeps 1..2: S(k-1) + z + T(k) + colsum(k) ============
  #pragma unroll
  for (int k=1;k<3;k++){
    const float rkm = (k==1)? r0 : r1;
    const float ib1m= (k==1)? i10 : i11;
    const float mum = (k==1)? mu0 : mu1;
    const float rk  = (k==1)? r1 : r2;
    const float ib1k= (k==1)? i11 : i12;
    const float ib2k= (k==1)? i21 : i22;
    const float b3k = (k==1)? b31 : b32;
    const float e3k = (k==1)? e31 : e32;
    float sp[16];
    #pragma unroll
    for (int j=0;j<16;j++) sp[j]=0.f;
    #pragma unroll
    for (int g=0; g<4; g++){
      if (4*g + sub < nv){
        const float* xp = xbase + (size_t)(4*g)*DD;
        float ss = 0.f;
        #pragma unroll
        for (int q=0;q<4;q++){
          const float4 lscq = *(const float4*)&colv[64*q + 4*c0];
          const float4 xv   = *(const float4*)(xp + 64*q);
          const float xvv[4]  = {xv.x, xv.y, xv.z, xv.w};
          const float lscv[4] = {lscq.x, lscq.y, lscq.z, lscq.w};
          const int aq[4] = {lo16(ap[g][q].x), hi16(ap[g][q].x),
                             lo16(ap[g][q].y), hi16(ap[g][q].y)};
          const int zq[4] = {lo16(zp[g][q].x), hi16(zp[g][q].x),
                             lo16(zp[g][q].y), hi16(zp[g][q].y)};
          int ny[4], nz[4];
          #pragma unroll
          for (int j=0;j<4;j++){
            const float lt = decq(aq[j]);
            float zf = zdec(zq[j]);
            const float ys  = (zf + rkm*lt) * ib1m;
            const float lsn = mum + ys - lscv[j];
            zf += rkm*(__expf(lt) - __expf(lsn));
            nz[j] = zenc(zf);
            const float y = (xvv[j] - zdec(nz[j]) + rk*lsn) * ib2k;
            ss += __expf(y);
            ny[j] = __float2int_rn(y*512.f);
          }
          ap[g][q].x = pk2(ny[0],ny[1]);
          ap[g][q].y = pk2(ny[2],ny[3]);
          zp[g][q].x = pk2(nz[0],nz[1]);
          zp[g][q].y = pk2(nz[2],nz[3]);
        }
        ss = grp_sum(ss);
        const float off = etag[g] - __logf(ss);
        const int offi = __float2int_rn(fmaxf(off, -56.f)*512.f);
        const unsigned offpk = pk2(offi, offi);
        #pragma unroll
        for (int q=0;q<4;q++){
          ap[g][q].x = pkadd_sat(ap[g][q].x, offpk);
          ap[g][q].y = pkadd_sat(ap[g][q].y, offpk);
          sp[4*q+0] += __expf((zdec(lo16(zp[g][q].x)) + rk*decq(lo16(ap[g][q].x))) * ib1k);
          sp[4*q+1] += __expf((zdec(hi16(zp[g][q].x)) + rk*decq(hi16(ap[g][q].x))) * ib1k);
          sp[4*q+2] += __expf((zdec(lo16(zp[g][q].y)) + rk*decq(lo16(ap[g][q].y))) * ib1k);
          sp[4*q+3] += __expf((zdec(hi16(zp[g][q].y)) + rk*decq(hi16(ap[g][q].y))) * ib1k);
        }
        const float en = (b3k*slqg[g] - z2g[g] + rk*etag[g]) * e3k;
        z2g[g] += rk*(__expf(en) - __expf(etag[g]));
        etag[g] = en;
      }
    }
    #pragma unroll
    for (int q=0;q<4;q++)
      *(float4*)&red[(4*w+sub)*RST + 64*q + 4*c0] =
          make_float4(sp[4*q], sp[4*q+1], sp[4*q+2], sp[4*q+3]);
    __syncthreads();
    if (tid < DD){
      float s = 0.f;
      #pragma unroll
      for (int i=0;i<32;i++) s += red[i*RST + tid];
      colv[tid] = __logf(s);
    }
    __syncthreads();
  }

  // ============ sweep 3: S(2) + z + T(3) + output ============
  {
    float op[16];
    #pragma unroll
    for (int j=0;j<16;j++) op[j]=0.f;
    #pragma unroll
    for (int g=0; g<4; g++){
      if (4*g + sub < nv){
        const float* xp = xbase + (size_t)(4*g)*DD;
        float ey[16];
        float ss = 0.f;
        #pragma unroll
        for (int q=0;q<4;q++){
          const float4 lscq = *(const float4*)&colv[64*q + 4*c0];
          const float4 xv   = *(const float4*)(xp + 64*q);
          const float xvv[4]  = {xv.x, xv.y, xv.z, xv.w};
          const float lscv[4] = {lscq.x, lscq.y, lscq.z, lscq.w};
          const int aq[4] = {lo16(ap[g][q].x), hi16(ap[g][q].x),
                             lo16(ap[g][q].y), hi16(ap[g][q].y)};
          const int zq[4] = {lo16(zp[g][q].x), hi16(zp[g][q].x),
                             lo16(zp[g][q].y), hi16(zp[g][q].y)};
          #pragma unroll
          for (int j=0;j<4;j++){
            const float lt = decq(aq[j]);
            float zf = zdec(zq[j]);
            const float ys  = (zf + r2*lt) * i12;
            const float lsn = mu2 + ys - lscv[j];
            zf += r2*(__expf(lt) - __expf(lsn));
            const float y = (xvv[j] - zf + r3*lsn) * i23;
            const float e = __expf(y);
            ey[4*q+j] = e;
            ss += e;
          }
        }
        ss = grp_sum(ss);
        const float rs = __expf(etag[g]) / ss;   // t = ey * exp(eta3)/se
        #pragma unroll
        for (int q=0;q<4;q++){
          const float4 xv = *(const float4*)(xp + 64*q);   // L1-hot reload
          op[4*q+0] += xv.x * ey[4*q+0] * rs;
          op[4*q+1] += xv.y * ey[4*q+1] * rs;
          op[4*q+2] += xv.z * ey[4*q+2] * rs;
          op[4*q+3] += xv.w * ey[4*q+3] * rs;
        }
      }
    }
    #pragma unroll
    for (int q=0;q<4;q++)
      *(float4*)&red[(4*w+sub)*RST + 64*q + 4*c0] =
          make_float4(op[4*q], op[4*q+1], op[4*q+2], op[4*q+3]);
    __syncthreads();
    if (tid < DD){
      float s = 0.f;
      #pragma unroll
      for (int i=0;i<32;i++) s += red[i*RST + tid];
      out[(size_t)b*DD + tid] = 256.0f * s;
    }
  }
}

extern "C" void kernel_launch(void* const* d_in, const int* in_sizes, int n_in,
                              void* d_out, int out_size, void* d_ws, size_t ws_size,
                              hipStream_t stream) {
  const float* x    = (const float*)d_in[0];
  const int*   batch= (const int*)d_in[1];
  const float* W1   = (const float*)d_in[2];
  const float* W2   = (const float*)d_in[3];
  const float* rho  = (const float*)d_in[4];
  const float* a1   = (const float*)d_in[5];
  const float* a2   = (const float*)d_in[6];
  const float* a3   = (const float*)d_in[7];
  float* out = (float*)d_out;
  const int T = in_sizes[1];   // total ragged rows

  float* logits = (float*)d_ws;              // T floats
  int*   starts = (int*)(logits + T);        // B+1 ints (padded to 1028)
  float* P      = (float*)(starts + 1028);   // 24 floats (padded to 32)
  unsigned short* w1b = (unsigned short*)(P + 32);  // 512*256 bf16

  const int zb = (T + 1023) / 1024;          // logits-zero blocks
  k_pre<<<70 + zb, 256, 0, stream>>>(W1, w1b, batch, T, starts, rho, a1, a2, a3, P, logits);
  k_mlp<<<dim3(4, (T+127)/128), 512, 0, stream>>>(x, w1b, W2, logits, T);
  k_solver<<<BB, 512, 0, stream>>>(x, logits, starts, P, out);
}

// Round 6
// 348.642 us; speedup vs baseline: 1.0421x; 1.0421x over previous
//
#include <hip/hip_runtime.h>
#include <math.h>

// Problem constants (fixed by reference): B=1024, NMAX=128, D=256, NUM=4
#define BB   1024
#define DD   256
#define LOGD 5.5451774444795624753f   // log(256)
#define RST  260                      // red row stride (floats): 260=4 mod 32 -> uniform banks

typedef __attribute__((ext_vector_type(8))) short short8;   // 8 bf16 = 4 VGPRs
typedef __attribute__((ext_vector_type(4))) float f32x4;    // MFMA acc

__device__ __forceinline__ float wave_sum(float v){
  #pragma unroll
  for (int off=32; off>0; off>>=1) v += __shfl_xor(v, off, 64);
  return v;
}
__device__ __forceinline__ float wave_max(float v){
  #pragma unroll
  for (int off=32; off>0; off>>=1) v = fmaxf(v, __shfl_xor(v, off, 64));
  return v;
}
// 16-lane-group sum: reduces 4 rows of a wave simultaneously (4-step chain)
__device__ __forceinline__ float grp_sum(float v){
  v += __shfl_xor(v, 1, 64);
  v += __shfl_xor(v, 2, 64);
  v += __shfl_xor(v, 4, 64);
  v += __shfl_xor(v, 8, 64);
  return v;
}
__device__ __forceinline__ float fast_tanh(float x){
  return 1.0f - 2.0f/(__expf(2.0f*x)+1.0f);
}
__device__ __forceinline__ unsigned short f2bf(float f){
  unsigned int u = __float_as_uint(f);
  unsigned int r = u + 0x7FFFu + ((u >> 16) & 1u);   // RNE
  return (unsigned short)(r >> 16);
}
// s16 codecs. A/log-state at scale 512 (abs err ~1e-3, range (-64,+16)).
// z at scale 4096 (|z| <= sum r_k ~ 3, abs err 1.2e-4).
__device__ __forceinline__ float decq(int q16){ return (float)q16 * (1.0f/512.0f); }
__device__ __forceinline__ int   zenc(float z){
  float t = fmaf(z, 4096.0f, 12582912.0f);   // RNE via 1.5*2^23 magic add
  return __float_as_int(t) - 0x4B400000;
}
__device__ __forceinline__ float zdec(int q){ return (float)q * (1.0f/4096.0f); }
__device__ __forceinline__ int lo16(unsigned u){ return ((int)(u<<16))>>16; }
__device__ __forceinline__ int hi16(unsigned u){ return ((int)u)>>16; }
__device__ __forceinline__ unsigned pk2(int a, int b){
  return ((unsigned)a & 0xffffu) | ((unsigned)b << 16);
}
// packed saturating s16 add: lt = sat(y_s16 + off_s16); sat(-32768)=-64.0 (==0 mass)
__device__ __forceinline__ unsigned pkadd_sat(unsigned a, unsigned b){
  unsigned d; asm("v_pk_add_i16 %0, %1, %2 clamp" : "=v"(d) : "v"(a), "v"(b)); return d;
}

// ---- K_pre: fused prologue (castW + bounds + params + logits zero) ----
// blocks 0..63: W1 cast; 64..68: segment bounds; 69: params; 70..: zero logits.
__global__ void k_pre(const float* __restrict__ W1, unsigned short* __restrict__ w1b,
                      const int* __restrict__ batch, int T, int* __restrict__ starts,
                      const float* __restrict__ rho, const float* __restrict__ a1,
                      const float* __restrict__ a2, const float* __restrict__ a3,
                      float* __restrict__ P, float* __restrict__ logits)
{
  const int blk = blockIdx.x, tid = threadIdx.x;
  if (blk < 64){
    const int t = blk*256 + tid;
    #pragma unroll
    for (int i=0;i<2;i++){
      const int idx = (t*2 + i)*4;
      const float4 v = *(const float4*)(W1 + idx);
      *(ushort4*)(w1b + idx) = make_ushort4(f2bf(v.x), f2bf(v.y), f2bf(v.z), f2bf(v.w));
    }
  } else if (blk < 69){
    const int b = (blk-64)*256 + tid;
    if (b <= BB){
      int lo = 0, hi = T;
      while (lo < hi){ int mid = (lo+hi)>>1; if (batch[mid] < b) lo = mid+1; else hi = mid; }
      starts[b] = lo;
    }
  } else if (blk == 69){
    if (tid == 0){
      float lm = -LOGD, z1 = 0.f;
      for (int k=0;k<4;k++){
        float r  = log1pf(expf(rho[k]));
        float b1 = log1pf(expf(a1[k]));
        float b2 = log1pf(expf(a2[k]));
        float b3 = log1pf(expf(a3[k]));
        P[k]    = r;
        P[4+k]  = 1.f/(b1+r);
        P[8+k]  = 1.f/(b2+r);
        P[12+k] = lm;              // mu used by S-update of iteration k
        P[16+k] = b3;
        P[20+k] = 1.f/(b3+r);
        float lmn = (b3*(-LOGD) - z1 + r*lm)/(b3+r);
        z1 += r*(expf(lmn)-expf(lm));
        lm = lmn;
      }
    }
  } else {
    // zero logits (replaces separate hipMemsetAsync launch)
    const int i = (blk-70)*1024 + tid*4;
    if (i + 3 < T){
      *(float4*)(logits + i) = make_float4(0.f,0.f,0.f,0.f);
    } else {
      for (int j=0; j<4 && i+j < T; j++) logits[i+j] = 0.f;
    }
  }
}

// ---- K2: fused MLP via bf16 MFMA ----
// Round-6: replaced __launch_bounds__(512,2) with explicit waves-per-eu range
// (4,8): the arg2 form pins BOTH the VGPR budget and the runtime residency at
// that level (rounds 1-5 evidence); the (min,max) attribute caps regs at
// 512/4=128 while letting the HW pack blocks freely up to 8 waves/EU.
__global__ __launch_bounds__(512) __attribute__((amdgpu_waves_per_eu(4, 8)))
void k_mlp(
    const float* __restrict__ x, const unsigned short* __restrict__ w1b,
    const float* __restrict__ W2, float* __restrict__ logits, int T)
{
#define LPW 72
  __shared__ unsigned short Xs[128*LPW];
  __shared__ unsigned short Ws[128*LPW];
  __shared__ float lred[128];
  const int by = blockIdx.x;
  const int bx = blockIdx.y;
  const int tid = threadIdx.x;
  if (tid < 128) lred[tid] = 0.f;

  const int l = tid & 63;
  const int w = tid >> 6;
  const int wm = w >> 2;
  const int wn = w & 3;
  const int lr = l & 15, quad = l >> 4;
  const int srow = tid >> 2;
  const int sseg = tid & 3;
  const int wrow = tid >> 3;
  const int wseg = tid & 7;

  f32x4 acc[4][2];
  #pragma unroll
  for (int mi=0;mi<4;mi++)
    #pragma unroll
    for (int ni=0;ni<2;ni++) acc[mi][ni] = (f32x4){0.f,0.f,0.f,0.f};

  for (int kt=0; kt<4; kt++){
    const int k0 = kt*64;
    {
      const int grow = bx*128 + srow;
      #pragma unroll
      for (int i=0;i<4;i++){
        float4 v = make_float4(0.f,0.f,0.f,0.f);
        if (grow < T) v = *(const float4*)(x + (size_t)grow*DD + k0 + sseg*16 + i*4);
        *(ushort4*)&Xs[srow*LPW + sseg*16 + i*4] =
            make_ushort4(f2bf(v.x), f2bf(v.y), f2bf(v.z), f2bf(v.w));
      }
    }
    #pragma unroll
    for (int h=0; h<2; h++){
      const int r = h*64 + wrow;
      *(short8*)&Ws[r*LPW + wseg*8] =
          *(const short8*)(w1b + (size_t)(by*128 + r)*DD + k0 + wseg*8);
    }
    __syncthreads();
    #pragma unroll
    for (int ks=0; ks<2; ks++){
      short8 afr[4], bfr[2];
      #pragma unroll
      for (int mi=0;mi<4;mi++)
        afr[mi] = *(const short8*)&Xs[(wm*64 + mi*16 + lr)*LPW + ks*32 + quad*8];
      #pragma unroll
      for (int ni=0;ni<2;ni++)
        bfr[ni] = *(const short8*)&Ws[(wn*32 + ni*16 + lr)*LPW + ks*32 + quad*8];
      #pragma unroll
      for (int mi=0;mi<4;mi++)
        #pragma unroll
        for (int ni=0;ni<2;ni++)
          acc[mi][ni] = __builtin_amdgcn_mfma_f32_16x16x32_bf16(afr[mi], bfr[ni], acc[mi][ni], 0, 0, 0);
    }
    __syncthreads();
  }

  float w2v[2];
  #pragma unroll
  for (int ni=0;ni<2;ni++) w2v[ni] = W2[by*128 + wn*32 + ni*16 + lr];
  #pragma unroll
  for (int mi=0;mi<4;mi++){
    float p[4];
    #pragma unroll
    for (int v=0; v<4; v++){
      p[v] = fast_tanh(acc[mi][0][v])*w2v[0] + fast_tanh(acc[mi][1][v])*w2v[1];
      #pragma unroll
      for (int off=1; off<16; off<<=1) p[v] += __shfl_xor(p[v], off, 64);
    }
    if (lr == 0){
      #pragma unroll
      for (int v=0; v<4; v++)
        atomicAdd(&lred[wm*64 + mi*16 + quad*4 + v], p[v]);
    }
  }
  __syncthreads();
  if (tid < 128){
    const int grow = bx*128 + tid;
    if (grow < T) atomicAdd(logits + grow, lred[tid]);
  }
}

// ---- K4: BADMM solver (round-4 structure, waves-per-eu range control) ----
// Round-5 post-mortem: spill gone (VGPR 72, WRITE 1MB) but dur 143us and
// occupancy 21.5% == exactly 1 block/CU resident, though resources allow 3.
// Unified 6-point theory: __launch_bounds__ arg2 pins waves/EU as a RANGE
// (VGPR budget AND residency cap): (1024,8)->32VGPR/70%, (512,4)->64cap/36%,
// (512,2)->128cap/21.5%(1 block). Fix: explicit amdgpu_waves_per_eu(4,8) --
// min 4/EU caps regs at 128 (demand ~72-110, no spill), max 8/EU lets the
// scheduler pack 2-4 blocks/CU by actual VGPR/LDS.
__global__ __launch_bounds__(512) __attribute__((amdgpu_waves_per_eu(4, 8)))
void k_solver(
    const float* __restrict__ x, const float* __restrict__ logits,
    const int* __restrict__ starts, const float* __restrict__ P,
    float* __restrict__ out)
{
  __shared__ __align__(16) float red[32*RST];   // 33280 B: column partials
  __shared__ __align__(16) float colv[DD];      // 1 KB: column log-sum
  const int b = blockIdx.x;
  const int start = starts[b];
  const int len = starts[b+1] - start;
  const int tid = threadIdx.x;
  const int w = tid >> 6, l = tid & 63;
  const int sub = l >> 4;          // row within 4-row group
  const int c0  = l & 15;          // column slice
  const int n0 = w*16;
  int nv = len - n0; nv = nv < 0 ? 0 : (nv > 16 ? 16 : nv);

  // scalar params (wave-uniform s_loads)
  const float r0=P[0], r1=P[1], r2=P[2], r3=P[3];
  const float i10=P[4], i11=P[5], i12=P[6];
  const float i20=P[8], i21=P[9], i22=P[10], i23=P[11];
  const float mu0=P[12], mu1=P[13], mu2=P[14];
  const float b30=P[16], b31=P[17], b32=P[18];
  const float e30=P[20], e31=P[21], e32=P[22];

  // ---- fused segment softmax (per-wave redundant) ----
  const float* lg = logits + start;
  float v0 = (l      < len) ? lg[l]    : -3.0e38f;
  float v1 = (l+64   < len) ? lg[l+64] : -3.0e38f;
  float sm = wave_max(fmaxf(v0,v1));
  float se0 = (l    < len) ? __expf(v0-sm) : 0.f;
  float se1 = (l+64 < len) ? __expf(v1-sm) : 0.f;
  float ssum0 = wave_sum(se0+se1);
  const float sinv = 1.f/(ssum0 + 1e-16f);
  const float esel = (n0 < 64) ? se0 : se1;   // rows n0..n0+15 on one side of 64

  // per-group (4 rows/wave-group) state, lane-redundant within 16-lane group
  float slqg[4], etag[4], z2g[4];
  uint2 ap[4][4];   // s16 log-state, [group][q]: 32 VGPR
  uint2 zp[4][4];   // s16 dual z:               32 VGPR
  #pragma unroll
  for (int g=0; g<4; g++){
    const int row = n0 + 4*g + sub;
    const float ev = __shfl(esel, row & 63, 64);
    const float lq = __logf(ev*sinv + 1e-8f);
    slqg[g] = lq; etag[g] = lq; z2g[g] = 0.f;
    #pragma unroll
    for (int q=0;q<4;q++){ zp[g][q].x = 0u; zp[g][q].y = 0u; }
  }

  const float* xbase = x + (size_t)(start + n0 + sub)*DD + 4*c0;

  // ================= sweep 0: T(0) + colsum for S(0) =================
  {
    float sp[16];
    #pragma unroll
    for (int j=0;j<16;j++) sp[j]=0.f;
    #pragma unroll
    for (int g=0; g<4; g++){
      if (4*g + sub < nv){
        const float* xp = xbase + (size_t)(4*g)*DD;
        const float a0 = slqg[g] - LOGD;
        float ss = 0.f;
        #pragma unroll
        for (int q=0;q<4;q++){
          const float4 xv = *(const float4*)(xp + 64*q);
          const float xvv[4] = {xv.x, xv.y, xv.z, xv.w};
          int ny[4];
          #pragma unroll
          for (int j=0;j<4;j++){
            const float y = (xvv[j] + r0*a0) * i20;
            ss += __expf(y);
            ny[j] = __float2int_rn(y*512.f);
          }
          ap[g][q].x = pk2(ny[0],ny[1]);
          ap[g][q].y = pk2(ny[2],ny[3]);
        }
        ss = grp_sum(ss);
        const float off = etag[g] - __logf(ss);
        const int offi = __float2int_rn(fmaxf(off, -56.f)*512.f);
        const unsigned offpk = pk2(offi, offi);
        #pragma unroll
        for (int q=0;q<4;q++){
          ap[g][q].x = pkadd_sat(ap[g][q].x, offpk);
          ap[g][q].y = pkadd_sat(ap[g][q].y, offpk);
          sp[4*q+0] += __expf((r0*decq(lo16(ap[g][q].x))) * i10);
          sp[4*q+1] += __expf((r0*decq(hi16(ap[g][q].x))) * i10);
          sp[4*q+2] += __expf((r0*decq(lo16(ap[g][q].y))) * i10);
          sp[4*q+3] += __expf((r0*decq(hi16(ap[g][q].y))) * i10);
        }
        const float en = (b30*slqg[g] - z2g[g] + r0*etag[g]) * e30;
        z2g[g] += r0*(__expf(en) - __expf(etag[g]));
        etag[g] = en;
      }
    }
    #pragma unroll
    for (int q=0;q<4;q++)
      *(float4*)&red[(4*w+sub)*RST + 64*q + 4*c0] =
          make_float4(sp[4*q], sp[4*q+1], sp[4*q+2], sp[4*q+3]);
  }
  __syncthreads();
  if (tid < DD){
    float s = 0.f;
    #pragma unroll
    for (int i=0;i<32;i++) s += red[i*RST + tid];
    colv[tid] = __logf(s);
  }
  __syncthreads();

  // ============ sweeps 1..2: S(k-1) + z + T(k) + colsum(k) ============
  #pragma unroll
  for (int k=1;k<3;k++){
    const float rkm = (k==1)? r0 : r1;
    const float ib1m= (k==1)? i10 : i11;
    const float mum = (k==1)? mu0 : mu1;
    const float rk  = (k==1)? r1 : r2;
    const float ib1k= (k==1)? i11 : i12;
    const float ib2k= (k==1)? i21 : i22;
    const float b3k = (k==1)? b31 : b32;
    const float e3k = (k==1)? e31 : e32;
    float sp[16];
    #pragma unroll
    for (int j=0;j<16;j++) sp[j]=0.f;
    #pragma unroll
    for (int g=0; g<4; g++){
      if (4*g + sub < nv){
        const float* xp = xbase + (size_t)(4*g)*DD;
        float ss = 0.f;
        #pragma unroll
        for (int q=0;q<4;q++){
          const float4 lscq = *(const float4*)&colv[64*q + 4*c0];
          const float4 xv   = *(const float4*)(xp + 64*q);
          const float xvv[4]  = {xv.x, xv.y, xv.z, xv.w};
          const float lscv[4] = {lscq.x, lscq.y, lscq.z, lscq.w};
          const int aq[4] = {lo16(ap[g][q].x), hi16(ap[g][q].x),
                             lo16(ap[g][q].y), hi16(ap[g][q].y)};
          const int zq[4] = {lo16(zp[g][q].x), hi16(zp[g][q].x),
                             lo16(zp[g][q].y), hi16(zp[g][q].y)};
          int ny[4], nz[4];
          #pragma unroll
          for (int j=0;j<4;j++){
            const float lt = decq(aq[j]);
            float zf = zdec(zq[j]);
            const float ys  = (zf + rkm*lt) * ib1m;
            const float lsn = mum + ys - lscv[j];
            zf += rkm*(__expf(lt) - __expf(lsn));
            nz[j] = zenc(zf);
            const float y = (xvv[j] - zdec(nz[j]) + rk*lsn) * ib2k;
            ss += __expf(y);
            ny[j] = __float2int_rn(y*512.f);
          }
          ap[g][q].x = pk2(ny[0],ny[1]);
          ap[g][q].y = pk2(ny[2],ny[3]);
          zp[g][q].x = pk2(nz[0],nz[1]);
          zp[g][q].y = pk2(nz[2],nz[3]);
        }
        ss = grp_sum(ss);
        const float off = etag[g] - __logf(ss);
        const int offi = __float2int_rn(fmaxf(off, -56.f)*512.f);
        const unsigned offpk = pk2(offi, offi);
        #pragma unroll
        for (int q=0;q<4;q++){
          ap[g][q].x = pkadd_sat(ap[g][q].x, offpk);
          ap[g][q].y = pkadd_sat(ap[g][q].y, offpk);
          sp[4*q+0] += __expf((zdec(lo16(zp[g][q].x)) + rk*decq(lo16(ap[g][q].x))) * ib1k);
          sp[4*q+1] += __expf((zdec(hi16(zp[g][q].x)) + rk*decq(hi16(ap[g][q].x))) * ib1k);
          sp[4*q+2] += __expf((zdec(lo16(zp[g][q].y)) + rk*decq(lo16(ap[g][q].y))) * ib1k);
          sp[4*q+3] += __expf((zdec(hi16(zp[g][q].y)) + rk*decq(hi16(ap[g][q].y))) * ib1k);
        }
        const float en = (b3k*slqg[g] - z2g[g] + rk*etag[g]) * e3k;
        z2g[g] += rk*(__expf(en) - __expf(etag[g]));
        etag[g] = en;
      }
    }
    #pragma unroll
    for (int q=0;q<4;q++)
      *(float4*)&red[(4*w+sub)*RST + 64*q + 4*c0] =
          make_float4(sp[4*q], sp[4*q+1], sp[4*q+2], sp[4*q+3]);
    __syncthreads();
    if (tid < DD){
      float s = 0.f;
      #pragma unroll
      for (int i=0;i<32;i++) s += red[i*RST + tid];
      colv[tid] = __logf(s);
    }
    __syncthreads();
  }

  // ============ sweep 3: S(2) + z + T(3) + output ============
  {
    float op[16];
    #pragma unroll
    for (int j=0;j<16;j++) op[j]=0.f;
    #pragma unroll
    for (int g=0; g<4; g++){
      if (4*g + sub < nv){
        const float* xp = xbase + (size_t)(4*g)*DD;
        float ey[16];
        float ss = 0.f;
        #pragma unroll
        for (int q=0;q<4;q++){
          const float4 lscq = *(const float4*)&colv[64*q + 4*c0];
          const float4 xv   = *(const float4*)(xp + 64*q);
          const float xvv[4]  = {xv.x, xv.y, xv.z, xv.w};
          const float lscv[4] = {lscq.x, lscq.y, lscq.z, lscq.w};
          const int aq[4] = {lo16(ap[g][q].x), hi16(ap[g][q].x),
                             lo16(ap[g][q].y), hi16(ap[g][q].y)};
          const int zq[4] = {lo16(zp[g][q].x), hi16(zp[g][q].x),
                             lo16(zp[g][q].y), hi16(zp[g][q].y)};
          #pragma unroll
          for (int j=0;j<4;j++){
            const float lt = decq(aq[j]);
            float zf = zdec(zq[j]);
            const float ys  = (zf + r2*lt) * i12;
            const float lsn = mu2 + ys - lscv[j];
            zf += r2*(__expf(lt) - __expf(lsn));
            const float y = (xvv[j] - zf + r3*lsn) * i23;
            const float e = __expf(y);
            ey[4*q+j] = e;
            ss += e;
          }
        }
        ss = grp_sum(ss);
        const float rs = __expf(etag[g]) / ss;   // t = ey * exp(eta3)/se
        #pragma unroll
        for (int q=0;q<4;q++){
          const float4 xv = *(const float4*)(xp + 64*q);   // L1-hot reload
          op[4*q+0] += xv.x * ey[4*q+0] * rs;
          op[4*q+1] += xv.y * ey[4*q+1] * rs;
          op[4*q+2] += xv.z * ey[4*q+2] * rs;
          op[4*q+3] += xv.w * ey[4*q+3] * rs;
        }
      }
    }
    #pragma unroll
    for (int q=0;q<4;q++)
      *(float4*)&red[(4*w+sub)*RST + 64*q + 4*c0] =
          make_float4(op[4*q], op[4*q+1], op[4*q+2], op[4*q+3]);
    __syncthreads();
    if (tid < DD){
      float s = 0.f;
      #pragma unroll
      for (int i=0;i<32;i++) s += red[i*RST + tid];
      out[(size_t)b*DD + tid] = 256.0f * s;
    }
  }
}

extern "C" void kernel_launch(void* const* d_in, const int* in_sizes, int n_in,
                              void* d_out, int out_size, void* d_ws, size_t ws_size,
                              hipStream_t stream) {
  const float* x    = (const float*)d_in[0];
  const int*   batch= (const int*)d_in[1];
  const float* W1   = (const float*)d_in[2];
  const float* W2   = (const float*)d_in[3];
  const float* rho  = (const float*)d_in[4];
  const float* a1   = (const float*)d_in[5];
  const float* a2   = (const float*)d_in[6];
  const float* a3   = (const float*)d_in[7];
  float* out = (float*)d_out;
  const int T = in_sizes[1];   // total ragged rows

  float* logits = (float*)d_ws;              // T floats
  int*   starts = (int*)(logits + T);        // B+1 ints (padded to 1028)
  float* P      = (float*)(starts + 1028);   // 24 floats (padded to 32)
  unsigned short* w1b = (unsigned short*)(P + 32);  // 512*256 bf16

  const int zb = (T + 1023) / 1024;          // logits-zero blocks
  k_pre<<<70 + zb, 256, 0, stream>>>(W1, w1b, batch, T, starts, rho, a1, a2, a3, P, logits);
  k_mlp<<<dim3(4, (T+127)/128), 512, 0, stream>>>(x, w1b, W2, logits, T);
  k_solver<<<BB, 512, 0, stream>>>(x, logits, starts, P, out);
}